// Round 1
// baseline (6583.337 us; speedup 1.0000x reference)
//
#include <hip/hip_runtime.h>

#define L_SEQ 512
#define BATCH 32
#define EMB 256
#define HID 256
#define G3 768
#define H2V 512
#define NFEAT 512

typedef __bf16 bf16x8 __attribute__((ext_vector_type(8)));
typedef float f32x4 __attribute__((ext_vector_type(4)));
typedef unsigned short u16;
typedef unsigned int u32;

__device__ __forceinline__ u16 f2bf(float f) {
  u32 u = __builtin_bit_cast(u32, f);
  u32 r = (u + 0x7fffu + ((u >> 16) & 1u)) >> 16;
  return (u16)r;
}
__device__ __forceinline__ float bf2f(u16 b) {
  return __builtin_bit_cast(float, ((u32)b) << 16);
}
__device__ __forceinline__ float sigf(float x) {
  return 1.0f / (1.0f + __expf(-x));
}

__global__ void k_cvt(const float* __restrict__ s, u16* __restrict__ d, int n) {
  int i = blockIdx.x * blockDim.x + threadIdx.x;
  int st = gridDim.x * blockDim.x;
  for (; i < n; i += st) d[i] = f2bf(s[i]);
}

__global__ __launch_bounds__(256) void k_embed(const int* __restrict__ ids,
    const float* __restrict__ emb, u16* __restrict__ x) {
  int blk = blockIdx.x;            // l*32 + b
  int l = blk >> 5, b = blk & 31;
  int row = ids[b * L_SEQ + l];
  x[(size_t)blk * EMB + threadIdx.x] = f2bf(emb[(size_t)row * EMB + threadIdx.x]);
}

// NT GEMM: C(M,N) = A(M,K)bf16 * B(N,K)bf16 (+bias). TRANS_B: B is (K,N) row-major.
// Tile 64x64, K-chunk 32, 4 waves: wave w owns M-subtile w, all 4 N-subtiles.
template<int TRANS_B, int C_BF16, int ADD_BIAS>
__global__ __launch_bounds__(256) void k_gemm(
    const u16* __restrict__ A, const u16* __restrict__ B, void* __restrict__ Cv,
    const float* __restrict__ bias, int K, int lda, int ldb, int ldc,
    long sA, long sB, long sC, long sBias)
{
  __shared__ __align__(16) u16 As[64][40];
  __shared__ __align__(16) u16 Bs[64][40];
  const int z = blockIdx.z;
  A += z * sA; B += z * sB;
  const int m0 = blockIdx.y * 64, n0 = blockIdx.x * 64;
  const int t = threadIdx.x;
  const int wave = t >> 6, lane = t & 63, lhi = lane >> 4, llo = lane & 15;
  f32x4 acc[4] = {};
  const int ar = t >> 2, ak = (t & 3) * 8;
  const int bkr = t >> 3, bnn = (t & 7) * 8;
  for (int k0 = 0; k0 < K; k0 += 32) {
    uint4 av = *(const uint4*)(A + (long)(m0 + ar) * lda + k0 + ak);
    *(uint4*)&As[ar][ak] = av;
    if (!TRANS_B) {
      uint4 bv = *(const uint4*)(B + (long)(n0 + ar) * ldb + k0 + ak);
      *(uint4*)&Bs[ar][ak] = bv;
    } else {
      uint4 bv = *(const uint4*)(B + (long)(k0 + bkr) * ldb + n0 + bnn);
      u16 tmp[8];
      *(uint4*)tmp = bv;
      #pragma unroll
      for (int i = 0; i < 8; i++) Bs[bnn + i][bkr] = tmp[i];
    }
    __syncthreads();
    bf16x8 a = __builtin_bit_cast(bf16x8, *(const uint4*)&As[16 * wave + llo][lhi * 8]);
    #pragma unroll
    for (int j = 0; j < 4; j++) {
      bf16x8 b = __builtin_bit_cast(bf16x8, *(const uint4*)&Bs[16 * j + llo][lhi * 8]);
      acc[j] = __builtin_amdgcn_mfma_f32_16x16x32_bf16(a, b, acc[j], 0, 0, 0);
    }
    __syncthreads();
  }
  #pragma unroll
  for (int j = 0; j < 4; j++) {
    float bv = 0.f;
    if (ADD_BIAS) bv = bias[z * sBias + n0 + 16 * j + llo];
    #pragma unroll
    for (int r = 0; r < 4; r++) {
      long row = m0 + 16 * wave + lhi * 4 + r;
      long col = n0 + 16 * j + llo;
      float vv = acc[j][r] + bv;
      if (C_BF16) ((u16*)Cv)[z * sC + row * ldc + col] = f2bf(vv);
      else        ((float*)Cv)[z * sC + row * ldc + col] = vv;
    }
  }
}

// GRU recurrence for one layer. grid = 4: blockIdx.x = dir*2 + batch_half.
// Each WG: M=16 batch rows, per step gh(16,768) = h(16,256)@Whh^T via MFMA,
// Whh streamed from L2 (bf16), gi precomputed (bias included), h kept bf16 in LDS.
__global__ __launch_bounds__(256) void k_gru(
    const u16* __restrict__ whh, const float* __restrict__ bhh,
    const u16* __restrict__ gi, const float* __restrict__ h0,
    u16* __restrict__ out)
{
  const int dir = blockIdx.x >> 1;
  const int b0 = (blockIdx.x & 1) * 16;
  __shared__ __align__(16) u16 h_lds[16][264];   // pad 8 -> 2-way (free) LDS access
  __shared__ float gh_lds[16][769];              // pad 1 -> conflict-free scatter
  const int t = threadIdx.x;
  const int wave = t >> 6, lane = t & 63, lhi = lane >> 4, llo = lane & 15;
  const int m = t & 15, c0 = (t >> 4) * 16;      // elementwise ownership: (batch m, comps c0..c0+15)
  const u16* whh_d = whh + dir * G3 * HID;
  const u16* gi_d = gi + (long)dir * L_SEQ * BATCH * G3;
  float bh[3][16];
  #pragma unroll
  for (int g = 0; g < 3; g++)
    #pragma unroll
    for (int i = 0; i < 16; i++)
      bh[g][i] = bhh[dir * G3 + g * HID + c0 + i];
  #pragma unroll
  for (int i = 0; i < 16; i++)
    h_lds[m][c0 + i] = f2bf(h0[(dir * BATCH + b0 + m) * HID + c0 + i]);
  __syncthreads();
  for (int s = 0; s < L_SEQ; s++) {
    const int l = dir ? (L_SEQ - 1 - s) : s;
    const long rowbase = ((long)l * BATCH + b0 + m) * G3;
    uint4 gv[6];                                  // prefetch gi for this step
    #pragma unroll
    for (int g = 0; g < 3; g++) {
      gv[2 * g]     = *(const uint4*)(gi_d + rowbase + g * HID + c0);
      gv[2 * g + 1] = *(const uint4*)(gi_d + rowbase + g * HID + c0 + 8);
    }
    f32x4 acc[12] = {};
    #pragma unroll
    for (int kt = 0; kt < 8; kt++) {
      bf16x8 a = __builtin_bit_cast(bf16x8, *(const uint4*)&h_lds[llo][kt * 32 + lhi * 8]);
      #pragma unroll
      for (int j = 0; j < 12; j++) {
        bf16x8 b = __builtin_bit_cast(bf16x8,
            *(const uint4*)(whh_d + (long)(192 * wave + 16 * j + llo) * HID + kt * 32 + lhi * 8));
        acc[j] = __builtin_amdgcn_mfma_f32_16x16x32_bf16(a, b, acc[j], 0, 0, 0);
      }
    }
    #pragma unroll
    for (int j = 0; j < 12; j++)
      #pragma unroll
      for (int r = 0; r < 4; r++)
        gh_lds[lhi * 4 + r][192 * wave + 16 * j + llo] = acc[j][r];
    __syncthreads();
    u16 gr[16], gz[16], gn[16], hnew[16];
    *(uint4*)&gr[0] = gv[0]; *(uint4*)&gr[8] = gv[1];
    *(uint4*)&gz[0] = gv[2]; *(uint4*)&gz[8] = gv[3];
    *(uint4*)&gn[0] = gv[4]; *(uint4*)&gn[8] = gv[5];
    #pragma unroll
    for (int i = 0; i < 16; i++) {
      int c = c0 + i;
      float rr = sigf(bf2f(gr[i]) + gh_lds[m][c] + bh[0][i]);
      float zz = sigf(bf2f(gz[i]) + gh_lds[m][HID + c] + bh[1][i]);
      float nn = bf2f(gn[i]) + rr * (gh_lds[m][2 * HID + c] + bh[2][i]);
      nn = 2.f * sigf(2.f * nn) - 1.f;           // tanh(x) = 2*sigmoid(2x)-1
      float hv = (1.f - zz) * nn + zz * bf2f(h_lds[m][c]);
      hnew[i] = f2bf(hv);
    }
    #pragma unroll
    for (int i = 0; i < 16; i++) h_lds[m][c0 + i] = hnew[i];
    u16* op = out + ((long)l * BATCH + b0 + m) * H2V + dir * HID + c0;
    *(uint4*)op = *(uint4*)&hnew[0];
    *(uint4*)(op + 8) = *(uint4*)&hnew[8];
    __syncthreads();
  }
}

__global__ __launch_bounds__(256) void k_softmax(float* __restrict__ e) {
  const int row = blockIdx.x * 4 + (threadIdx.x >> 6);
  const int lane = threadIdx.x & 63;
  float* p = e + (long)row * NFEAT;
  float v[8];
  #pragma unroll
  for (int i = 0; i < 8; i++) v[i] = p[lane + 64 * i];
  float mx = v[0];
  #pragma unroll
  for (int i = 1; i < 8; i++) mx = fmaxf(mx, v[i]);
  #pragma unroll
  for (int o = 1; o < 64; o <<= 1) mx = fmaxf(mx, __shfl_xor(mx, o, 64));
  float sum = 0.f;
  #pragma unroll
  for (int i = 0; i < 8; i++) { v[i] = __expf(v[i] - mx); sum += v[i]; }
  #pragma unroll
  for (int o = 1; o < 64; o <<= 1) sum += __shfl_xor(sum, o, 64);
  float inv = 1.0f / sum;
  #pragma unroll
  for (int i = 0; i < 8; i++) p[lane + 64 * i] = v[i] * inv;
}

// energy(L,B,F) probs -> attn_out (B,F,L) fp32 and Pb (B,F,L) bf16
__global__ __launch_bounds__(256) void k_transpose(const float* __restrict__ P,
    float* __restrict__ aout, u16* __restrict__ Pb)
{
  const int l0 = blockIdx.x * 64, f0 = blockIdx.y * 64, b = blockIdx.z;
  __shared__ float tile[64][65];
  const int t = threadIdx.x;
  const int ci = t & 63, q = t >> 6;
  #pragma unroll
  for (int s2 = 0; s2 < 16; s2++) {
    int li = q * 16 + s2;
    tile[li][ci] = P[((long)(l0 + li) * BATCH + b) * NFEAT + f0 + ci];
  }
  __syncthreads();
  #pragma unroll
  for (int s2 = 0; s2 < 16; s2++) {
    int f = q * 16 + s2;
    float val = tile[ci][f];
    long idx = ((long)b * NFEAT + f0 + f) * L_SEQ + l0 + ci;
    aout[idx] = val;
    Pb[idx] = f2bf(val);
  }
}

extern "C" void kernel_launch(void* const* d_in, const int* in_sizes, int n_in,
                              void* d_out, int out_size, void* d_ws, size_t ws_size,
                              hipStream_t stream)
{
  const int* ids      = (const int*)d_in[0];
  const float* hidden = (const float*)d_in[2];
  const float* fe     = (const float*)d_in[3];
  const float* emb    = (const float*)d_in[4];
  const float* wih0   = (const float*)d_in[5];
  const float* whh0   = (const float*)d_in[6];
  const float* bih0   = (const float*)d_in[7];
  const float* bhh0   = (const float*)d_in[8];
  const float* wih1   = (const float*)d_in[9];
  const float* whh1   = (const float*)d_in[10];
  const float* bih1   = (const float*)d_in[11];
  const float* bhh1   = (const float*)d_in[12];
  const float* law    = (const float*)d_in[13];
  const float* lab    = (const float*)d_in[14];
  const float* faw    = (const float*)d_in[15];
  const float* fab    = (const float*)d_in[16];
  const float* vmat   = (const float*)d_in[17];

  char* w = (char*)d_ws;
  size_t o = 0;
  auto alloc = [&](size_t elems, size_t esz) {
    void* p = w + o; o = (o + elems * esz + 255) & ~(size_t)255; return p;
  };
  u16* wih0b = (u16*)alloc((size_t)2 * 768 * 256, 2);
  u16* whh0b = (u16*)alloc((size_t)2 * 768 * 256, 2);
  u16* wih1b = (u16*)alloc((size_t)2 * 768 * 512, 2);
  u16* whh1b = (u16*)alloc((size_t)2 * 768 * 256, 2);
  u16* lawb  = (u16*)alloc((size_t)256 * 512, 2);
  u16* fawb  = (u16*)alloc((size_t)256 * 512, 2);
  u16* vb    = (u16*)alloc((size_t)128 * 256, 2);
  u16* feb   = (u16*)alloc((size_t)384 * 256, 2);
  u16* xb    = (u16*)alloc((size_t)16384 * 256, 2);
  u16* gi0   = (u16*)alloc((size_t)2 * 16384 * 768, 2);
  u16* out0  = (u16*)alloc((size_t)16384 * 512, 2);
  u16* gi1   = (u16*)alloc((size_t)2 * 16384 * 768, 2);
  u16* rnn   = (u16*)alloc((size_t)16384 * 512, 2);
  u16* wh    = (u16*)alloc((size_t)16384 * 256, 2);
  u16* wh2   = (u16*)alloc((size_t)16384 * 256, 2);
  float* energy = (float*)alloc((size_t)16384 * 512, 4);
  u16* Pb    = (u16*)alloc((size_t)16384 * 512, 2);

  k_cvt<<<96, 256, 0, stream>>>(wih0, wih0b, 2 * 768 * 256);
  k_cvt<<<96, 256, 0, stream>>>(whh0, whh0b, 2 * 768 * 256);
  k_cvt<<<192, 256, 0, stream>>>(wih1, wih1b, 2 * 768 * 512);
  k_cvt<<<96, 256, 0, stream>>>(whh1, whh1b, 2 * 768 * 256);
  k_cvt<<<32, 256, 0, stream>>>(law, lawb, 256 * 512);
  k_cvt<<<32, 256, 0, stream>>>(faw, fawb, 256 * 512);
  k_cvt<<<8, 256, 0, stream>>>(vmat, vb, 128 * 256);
  k_cvt<<<24, 256, 0, stream>>>(fe, feb, 384 * 256);
  k_embed<<<16384, 256, 0, stream>>>(ids, emb, xb);

  // gi0 = x @ wih0^T + bih0, per dir (z=2): C bf16 (2,L,B,768)
  k_gemm<0, 1, 1><<<dim3(12, 256, 2), 256, 0, stream>>>(xb, wih0b, gi0, bih0,
      256, 256, 256, 768, 0L, 768L * 256, (long)16384 * 768, 768L);
  k_gru<<<4, 256, 0, stream>>>(whh0b, bhh0, gi0, hidden, out0);

  // gi1 = out0 @ wih1^T + bih1
  k_gemm<0, 1, 1><<<dim3(12, 256, 2), 256, 0, stream>>>(out0, wih1b, gi1, bih1,
      512, 512, 512, 768, 0L, 768L * 512, (long)16384 * 768, 768L);
  k_gru<<<4, 256, 0, stream>>>(whh1b, bhh1, gi1, hidden + 2 * 32 * 256, rnn);

  // wh = rnn @ la_w^T + la_b (bf16), wh2 = rnn @ fa_w^T + fa_b (bf16)
  k_gemm<0, 1, 1><<<dim3(4, 256, 1), 256, 0, stream>>>(rnn, lawb, wh, lab,
      512, 512, 512, 256, 0L, 0L, 0L, 0L);
  k_gemm<0, 1, 1><<<dim3(4, 256, 1), 256, 0, stream>>>(rnn, fawb, wh2, fab,
      512, 512, 512, 256, 0L, 0L, 0L, 0L);
  // vwh -> energy[:,384:512] ; fwh -> energy[:,0:384]  (fp32)
  k_gemm<0, 0, 0><<<dim3(2, 256, 1), 256, 0, stream>>>(wh, vb, energy + 384, nullptr,
      256, 256, 256, 512, 0L, 0L, 0L, 0L);
  k_gemm<0, 0, 0><<<dim3(6, 256, 1), 256, 0, stream>>>(wh2, feb, energy, nullptr,
      256, 256, 256, 512, 0L, 0L, 0L, 0L);

  k_softmax<<<4096, 256, 0, stream>>>(energy);

  float* attn_out = (float*)d_out + (size_t)32 * 512 * 512;
  k_transpose<<<dim3(8, 8, 32), 256, 0, stream>>>(energy, attn_out, Pb);

  // context[b] = P[b](F,L) @ rnn(:,b,:)(L,2H)  -> d_out (B,F,2H) fp32
  k_gemm<1, 0, 0><<<dim3(8, 8, 32), 256, 0, stream>>>(Pb, rnn, (float*)d_out, nullptr,
      512, 512, 16384, 512, (long)512 * 512, 512L, (long)512 * 512, 0L);
}

// Round 2
// 3130.564 us; speedup vs baseline: 2.1029x; 2.1029x over previous
//
#include <hip/hip_runtime.h>

#define L_SEQ 512
#define BATCH 32
#define EMB 256
#define HID 256
#define G3 768
#define H2V 512
#define NFEAT 512

typedef __bf16 bf16x8 __attribute__((ext_vector_type(8)));
typedef float f32x4 __attribute__((ext_vector_type(4)));
typedef unsigned short u16;
typedef unsigned int u32;

__device__ __forceinline__ u16 f2bf(float f) {
  u32 u = __builtin_bit_cast(u32, f);
  u32 r = (u + 0x7fffu + ((u >> 16) & 1u)) >> 16;
  return (u16)r;
}
__device__ __forceinline__ float bf2f(u16 b) {
  return __builtin_bit_cast(float, ((u32)b) << 16);
}
__device__ __forceinline__ float sigf(float x) {
  return 1.0f / (1.0f + __expf(-x));
}

__global__ void k_cvt(const float* __restrict__ s, u16* __restrict__ d, int n) {
  int i = blockIdx.x * blockDim.x + threadIdx.x;
  int st = gridDim.x * blockDim.x;
  for (; i < n; i += st) d[i] = f2bf(s[i]);
}

__global__ void k_mkbias(const float* __restrict__ bih, const float* __restrict__ bhh,
                         float* __restrict__ cb) {
  int d = blockIdx.x, t = threadIdx.x;
  float v = bih[d * G3 + t];
  if (t < 512) v += bhh[d * G3 + t];     // bhh_r, bhh_z additive pre-sigmoid; bhh_n NOT foldable
  cb[d * G3 + t] = v;
}

__global__ __launch_bounds__(256) void k_embed(const int* __restrict__ ids,
    const float* __restrict__ emb, u16* __restrict__ x) {
  int blk = blockIdx.x;            // l*32 + b
  int l = blk >> 5, b = blk & 31;
  int row = ids[b * L_SEQ + l];
  x[(size_t)blk * EMB + threadIdx.x] = f2bf(emb[(size_t)row * EMB + threadIdx.x]);
}

// NT GEMM: C(M,N) = A(M,K)bf16 * B(N,K)bf16 (+bias). TRANS_B: B is (K,N) row-major.
// C_MODE: 0 = fp32, 1 = bf16, 2 = bf16 packed for k_gru's per-lane gi layout.
template<int TRANS_B, int C_MODE, int ADD_BIAS>
__global__ __launch_bounds__(256) void k_gemm(
    const u16* __restrict__ A, const u16* __restrict__ B, void* __restrict__ Cv,
    const float* __restrict__ bias, int K, int lda, int ldb, int ldc,
    long sA, long sB, long sC, long sBias)
{
  __shared__ __align__(16) u16 As[64][40];
  __shared__ __align__(16) u16 Bs[64][40];
  const int z = blockIdx.z;
  A += z * sA; B += z * sB;
  const int m0 = blockIdx.y * 64, n0 = blockIdx.x * 64;
  const int t = threadIdx.x;
  const int wave = t >> 6, lane = t & 63, lhi = lane >> 4, llo = lane & 15;
  f32x4 acc[4] = {};
  const int ar = t >> 2, ak = (t & 3) * 8;
  const int bkr = t >> 3, bnn = (t & 7) * 8;
  for (int k0 = 0; k0 < K; k0 += 32) {
    uint4 av = *(const uint4*)(A + (long)(m0 + ar) * lda + k0 + ak);
    *(uint4*)&As[ar][ak] = av;
    if (!TRANS_B) {
      uint4 bv = *(const uint4*)(B + (long)(n0 + ar) * ldb + k0 + ak);
      *(uint4*)&Bs[ar][ak] = bv;
    } else {
      uint4 bv = *(const uint4*)(B + (long)(k0 + bkr) * ldb + n0 + bnn);
      u16 tmp[8];
      *(uint4*)tmp = bv;
      #pragma unroll
      for (int i = 0; i < 8; i++) Bs[bnn + i][bkr] = tmp[i];
    }
    __syncthreads();
    bf16x8 a = __builtin_bit_cast(bf16x8, *(const uint4*)&As[16 * wave + llo][lhi * 8]);
    #pragma unroll
    for (int j = 0; j < 4; j++) {
      bf16x8 b = __builtin_bit_cast(bf16x8, *(const uint4*)&Bs[16 * j + llo][lhi * 8]);
      acc[j] = __builtin_amdgcn_mfma_f32_16x16x32_bf16(a, b, acc[j], 0, 0, 0);
    }
    __syncthreads();
  }
  #pragma unroll
  for (int j = 0; j < 4; j++) {
    float bv = 0.f;
    if (ADD_BIAS) bv = bias[z * sBias + n0 + 16 * j + llo];
    #pragma unroll
    for (int r = 0; r < 4; r++) {
      long row = m0 + 16 * wave + lhi * 4 + r;
      long col = n0 + 16 * j + llo;
      float vv = acc[j][r] + bv;
      if (C_MODE == 2) {
        // pack for k_gru: dir z, l = row>>5, b = row&31, g = col>>8, cc = col&255
        int b = (int)(row & 31);
        long l = row >> 5;
        int cc = (int)(col & 255), g = (int)(col >> 8);
        long idx = ((l * 2 + (b >> 4)) * 512 + (cc >> 5) * 64 + ((b & 15) >> 2) * 16 + (cc & 15)) * 24
                   + g * 8 + ((cc >> 4) & 1) * 4 + (b & 3);
        ((u16*)Cv)[z * sC + idx] = f2bf(vv);
      } else if (C_MODE == 1) {
        ((u16*)Cv)[z * sC + row * ldc + col] = f2bf(vv);
      } else {
        ((float*)Cv)[z * sC + row * ldc + col] = vv;
      }
    }
  }
}

// GRU recurrence, weights register/LDS-resident. grid = 4: blockIdx.x = dir*2 + half.
// 512 threads (8 waves, 2/SIMD). Wave w owns gh columns [32w,32w+32) for ALL 3 gates:
// 6 N-tiles of 16; tiles 0..4 + half of tile 5 in VGPRs, rest of tile 5 in LDS.
// Gates computed directly on MFMA acc (C layout); h double-buffered in LDS; 1 barrier/step.
__global__ __launch_bounds__(512, 2) void k_gru(
    const u16* __restrict__ whh, const float* __restrict__ bhh,
    const u16* __restrict__ gi, const float* __restrict__ h0,
    u16* __restrict__ out)
{
  const int dir = blockIdx.x >> 1;
  const int half = blockIdx.x & 1;
  const int b0 = half * 16;
  __shared__ __align__(16) u16 h_lds[2][16][264];
  __shared__ __align__(16) uint4 ldsB[8][4][64];   // [wave][kt-4][lane]
  const int t = threadIdx.x;
  const int w = t >> 6, lane = t & 63, lhi = lane >> 4, llo = lane & 15;
  const u16* whh_d = whh + dir * G3 * HID;
  const u16* gi_d = gi + (size_t)dir * 12582912;

  // ---- weight preload: tile tt = g*2+jj -> weight rows (g*256 + 32w + 16jj + llo)
  uint4 breg[5][8];
  uint4 breg5[4];
  #pragma unroll
  for (int tt = 0; tt < 5; tt++) {
    const int g = tt >> 1, jj = tt & 1;
    const u16* bp = whh_d + (size_t)(g * 256 + 32 * w + 16 * jj + llo) * HID + lhi * 8;
    #pragma unroll
    for (int kt = 0; kt < 8; kt++) breg[tt][kt] = *(const uint4*)(bp + kt * 32);
  }
  {
    const u16* bp = whh_d + (size_t)(512 + 32 * w + 16 + llo) * HID + lhi * 8;
    #pragma unroll
    for (int kt = 0; kt < 4; kt++) breg5[kt] = *(const uint4*)(bp + kt * 32);
    #pragma unroll
    for (int kt = 4; kt < 8; kt++) ldsB[w][kt - 4][lane] = *(const uint4*)(bp + kt * 32);
  }
  // ---- h0 -> h_lds[0]
  {
    int m = t >> 5, c0 = (t & 31) * 8;
    const float* hp = h0 + (size_t)(dir * BATCH + b0 + m) * HID + c0;
    float4 f0 = *(const float4*)(hp);
    float4 f1 = *(const float4*)(hp + 4);
    u16 hh[8] = {f2bf(f0.x), f2bf(f0.y), f2bf(f0.z), f2bf(f0.w),
                 f2bf(f1.x), f2bf(f1.y), f2bf(f1.z), f2bf(f1.w)};
    *(uint4*)&h_lds[0][m][c0] = *(uint4*)hh;
  }
  // n-gate bias, folded into acc init (gh_n = h@Wn^T + bhh_n)
  const float bn0 = bhh[dir * G3 + 512 + 32 * w + llo];
  const float bn1 = bhh[dir * G3 + 512 + 32 * w + 16 + llo];
  __syncthreads();

  for (int s = 0; s < L_SEQ; s++) {
    const int rd = s & 1, wr = rd ^ 1;
    const int l = dir ? (L_SEQ - 1 - s) : s;
    // gi prefetch: packed per-lane layout, fully coalesced, issued before MFMA
    const u16* gp = gi_d + (((size_t)l * 2 + half) * 512 + t) * 24;
    uint4 q0 = *(const uint4*)(gp);
    uint4 q1 = *(const uint4*)(gp + 8);
    uint4 q2 = *(const uint4*)(gp + 16);

    f32x4 acc[6];
    #pragma unroll
    for (int tt = 0; tt < 4; tt++) acc[tt] = (f32x4){0.f, 0.f, 0.f, 0.f};
    acc[4] = (f32x4){bn0, bn0, bn0, bn0};
    acc[5] = (f32x4){bn1, bn1, bn1, bn1};
    #pragma unroll
    for (int kt = 0; kt < 8; kt++) {
      bf16x8 a = __builtin_bit_cast(bf16x8, *(const uint4*)&h_lds[rd][llo][kt * 32 + lhi * 8]);
      uint4 b5 = (kt < 4) ? breg5[kt] : ldsB[w][kt - 4][lane];
      #pragma unroll
      for (int tt = 0; tt < 5; tt++)
        acc[tt] = __builtin_amdgcn_mfma_f32_16x16x32_bf16(
            a, __builtin_bit_cast(bf16x8, breg[tt][kt]), acc[tt], 0, 0, 0);
      acc[5] = __builtin_amdgcn_mfma_f32_16x16x32_bf16(
          a, __builtin_bit_cast(bf16x8, b5), acc[5], 0, 0, 0);
    }

    u16 __attribute__((aligned(16))) arr[24];
    *(uint4*)&arr[0] = q0;
    *(uint4*)&arr[8] = q1;
    *(uint4*)&arr[16] = q2;
    #pragma unroll
    for (int jj = 0; jj < 2; jj++) {
      #pragma unroll
      for (int r_ = 0; r_ < 4; r_++) {
        const int row = lhi * 4 + r_;
        const int col = 32 * w + 16 * jj + llo;
        float rr = sigf(bf2f(arr[jj * 4 + r_]) + acc[jj][r_]);
        float zz = sigf(bf2f(arr[8 + jj * 4 + r_]) + acc[2 + jj][r_]);
        float p = bf2f(arr[16 + jj * 4 + r_]) + rr * acc[4 + jj][r_];
        float nn = 2.f * sigf(2.f * p) - 1.f;      // tanh
        float hold = bf2f(h_lds[rd][row][col]);
        float hv = nn + zz * (hold - nn);
        u16 hb = f2bf(hv);
        h_lds[wr][row][col] = hb;
        out[((size_t)l * BATCH + b0 + row) * H2V + dir * HID + col] = hb;
      }
    }
    __syncthreads();
  }
}

__global__ __launch_bounds__(256) void k_softmax(float* __restrict__ e) {
  const int row = blockIdx.x * 4 + (threadIdx.x >> 6);
  const int lane = threadIdx.x & 63;
  float* p = e + (long)row * NFEAT;
  float v[8];
  #pragma unroll
  for (int i = 0; i < 8; i++) v[i] = p[lane + 64 * i];
  float mx = v[0];
  #pragma unroll
  for (int i = 1; i < 8; i++) mx = fmaxf(mx, v[i]);
  #pragma unroll
  for (int o = 1; o < 64; o <<= 1) mx = fmaxf(mx, __shfl_xor(mx, o, 64));
  float sum = 0.f;
  #pragma unroll
  for (int i = 0; i < 8; i++) { v[i] = __expf(v[i] - mx); sum += v[i]; }
  #pragma unroll
  for (int o = 1; o < 64; o <<= 1) sum += __shfl_xor(sum, o, 64);
  float inv = 1.0f / sum;
  #pragma unroll
  for (int i = 0; i < 8; i++) p[lane + 64 * i] = v[i] * inv;
}

// energy(L,B,F) probs -> attn_out (B,F,L) fp32 and Pb (B,F,L) bf16
__global__ __launch_bounds__(256) void k_transpose(const float* __restrict__ P,
    float* __restrict__ aout, u16* __restrict__ Pb)
{
  const int l0 = blockIdx.x * 64, f0 = blockIdx.y * 64, b = blockIdx.z;
  __shared__ float tile[64][65];
  const int t = threadIdx.x;
  const int ci = t & 63, q = t >> 6;
  #pragma unroll
  for (int s2 = 0; s2 < 16; s2++) {
    int li = q * 16 + s2;
    tile[li][ci] = P[((long)(l0 + li) * BATCH + b) * NFEAT + f0 + ci];
  }
  __syncthreads();
  #pragma unroll
  for (int s2 = 0; s2 < 16; s2++) {
    int f = q * 16 + s2;
    float val = tile[ci][f];
    long idx = ((long)b * NFEAT + f0 + f) * L_SEQ + l0 + ci;
    aout[idx] = val;
    Pb[idx] = f2bf(val);
  }
}

extern "C" void kernel_launch(void* const* d_in, const int* in_sizes, int n_in,
                              void* d_out, int out_size, void* d_ws, size_t ws_size,
                              hipStream_t stream)
{
  const int* ids      = (const int*)d_in[0];
  const float* hidden = (const float*)d_in[2];
  const float* fe     = (const float*)d_in[3];
  const float* emb    = (const float*)d_in[4];
  const float* wih0   = (const float*)d_in[5];
  const float* whh0   = (const float*)d_in[6];
  const float* bih0   = (const float*)d_in[7];
  const float* bhh0   = (const float*)d_in[8];
  const float* wih1   = (const float*)d_in[9];
  const float* whh1   = (const float*)d_in[10];
  const float* bih1   = (const float*)d_in[11];
  const float* bhh1   = (const float*)d_in[12];
  const float* law    = (const float*)d_in[13];
  const float* lab    = (const float*)d_in[14];
  const float* faw    = (const float*)d_in[15];
  const float* fab    = (const float*)d_in[16];
  const float* vmat   = (const float*)d_in[17];

  char* w = (char*)d_ws;
  size_t o = 0;
  auto alloc = [&](size_t elems, size_t esz) {
    void* p = w + o; o = (o + elems * esz + 255) & ~(size_t)255; return p;
  };
  u16* wih0b = (u16*)alloc((size_t)2 * 768 * 256, 2);
  u16* whh0b = (u16*)alloc((size_t)2 * 768 * 256, 2);
  u16* wih1b = (u16*)alloc((size_t)2 * 768 * 512, 2);
  u16* whh1b = (u16*)alloc((size_t)2 * 768 * 256, 2);
  u16* lawb  = (u16*)alloc((size_t)256 * 512, 2);
  u16* fawb  = (u16*)alloc((size_t)256 * 512, 2);
  u16* vb    = (u16*)alloc((size_t)128 * 256, 2);
  u16* feb   = (u16*)alloc((size_t)384 * 256, 2);
  u16* xb    = (u16*)alloc((size_t)16384 * 256, 2);
  u16* gi0   = (u16*)alloc((size_t)2 * 16384 * 768, 2);
  u16* out0  = (u16*)alloc((size_t)16384 * 512, 2);
  u16* gi1   = (u16*)alloc((size_t)2 * 16384 * 768, 2);
  u16* rnn   = (u16*)alloc((size_t)16384 * 512, 2);
  u16* wh    = (u16*)alloc((size_t)16384 * 256, 2);
  u16* wh2   = (u16*)alloc((size_t)16384 * 256, 2);
  float* energy = (float*)alloc((size_t)16384 * 512, 4);
  u16* Pb    = (u16*)alloc((size_t)16384 * 512, 2);
  float* cbias0 = (float*)alloc((size_t)2 * 768, 4);
  float* cbias1 = (float*)alloc((size_t)2 * 768, 4);

  k_cvt<<<96, 256, 0, stream>>>(wih0, wih0b, 2 * 768 * 256);
  k_cvt<<<96, 256, 0, stream>>>(whh0, whh0b, 2 * 768 * 256);
  k_cvt<<<192, 256, 0, stream>>>(wih1, wih1b, 2 * 768 * 512);
  k_cvt<<<96, 256, 0, stream>>>(whh1, whh1b, 2 * 768 * 256);
  k_cvt<<<32, 256, 0, stream>>>(law, lawb, 256 * 512);
  k_cvt<<<32, 256, 0, stream>>>(faw, fawb, 256 * 512);
  k_cvt<<<8, 256, 0, stream>>>(vmat, vb, 128 * 256);
  k_cvt<<<24, 256, 0, stream>>>(fe, feb, 384 * 256);
  k_mkbias<<<2, 768, 0, stream>>>(bih0, bhh0, cbias0);
  k_mkbias<<<2, 768, 0, stream>>>(bih1, bhh1, cbias1);
  k_embed<<<16384, 256, 0, stream>>>(ids, emb, xb);

  // gi0 = x @ wih0^T + (bih0 + bhh0[r,z]) packed for k_gru
  k_gemm<0, 2, 1><<<dim3(12, 256, 2), 256, 0, stream>>>(xb, wih0b, gi0, cbias0,
      256, 256, 256, 768, 0L, 768L * 256, 12582912L, 768L);
  k_gru<<<4, 512, 0, stream>>>(whh0b, bhh0, gi0, hidden, out0);

  // gi1 = out0 @ wih1^T + (bih1 + bhh1[r,z]) packed
  k_gemm<0, 2, 1><<<dim3(12, 256, 2), 256, 0, stream>>>(out0, wih1b, gi1, cbias1,
      512, 512, 512, 768, 0L, 768L * 512, 12582912L, 768L);
  k_gru<<<4, 512, 0, stream>>>(whh1b, bhh1, gi1, hidden + 2 * 32 * 256, rnn);

  // wh = rnn @ la_w^T + la_b (bf16), wh2 = rnn @ fa_w^T + fa_b (bf16)
  k_gemm<0, 1, 1><<<dim3(4, 256, 1), 256, 0, stream>>>(rnn, lawb, wh, lab,
      512, 512, 512, 256, 0L, 0L, 0L, 0L);
  k_gemm<0, 1, 1><<<dim3(4, 256, 1), 256, 0, stream>>>(rnn, fawb, wh2, fab,
      512, 512, 512, 256, 0L, 0L, 0L, 0L);
  // vwh -> energy[:,384:512] ; fwh -> energy[:,0:384]  (fp32)
  k_gemm<0, 0, 0><<<dim3(2, 256, 1), 256, 0, stream>>>(wh, vb, energy + 384, nullptr,
      256, 256, 256, 512, 0L, 0L, 0L, 0L);
  k_gemm<0, 0, 0><<<dim3(6, 256, 1), 256, 0, stream>>>(wh2, feb, energy, nullptr,
      256, 256, 256, 512, 0L, 0L, 0L, 0L);

  k_softmax<<<4096, 256, 0, stream>>>(energy);

  float* attn_out = (float*)d_out + (size_t)32 * 512 * 512;
  k_transpose<<<dim3(8, 8, 32), 256, 0, stream>>>(energy, attn_out, Pb);

  // context[b] = P[b](F,L) @ rnn(:,b,:)(L,2H)  -> d_out (B,F,2H) fp32
  k_gemm<1, 0, 0><<<dim3(8, 8, 32), 256, 0, stream>>>(Pb, rnn, (float*)d_out, nullptr,
      512, 512, 16384, 512, (long)512 * 512, 512L, (long)512 * 512, 0L);
}

// Round 3
// 2148.164 us; speedup vs baseline: 3.0646x; 1.4573x over previous
//
#include <hip/hip_runtime.h>

#define L_SEQ 512
#define BATCH 32
#define EMB 256
#define HID 256
#define G3 768
#define H2V 512
#define NFEAT 512
#define LOG2E 1.44269504f

typedef __bf16 bf16x8 __attribute__((ext_vector_type(8)));
typedef float f32x4 __attribute__((ext_vector_type(4)));
typedef unsigned short u16;
typedef unsigned int u32;

__device__ __forceinline__ u16 f2bf(float f) {
  u32 u = __builtin_bit_cast(u32, f);
  u32 r = (u + 0x7fffu + ((u >> 16) & 1u)) >> 16;
  return (u16)r;
}
__device__ __forceinline__ float bf2f(u16 b) {
  return __builtin_bit_cast(float, ((u32)b) << 16);
}

__global__ void k_cvt(const float* __restrict__ s, u16* __restrict__ d, int n, float scale) {
  int i = blockIdx.x * blockDim.x + threadIdx.x;
  int st = gridDim.x * blockDim.x;
  for (; i < n; i += st) d[i] = f2bf(s[i] * scale);
}

__global__ void k_mkbias(const float* __restrict__ bih, const float* __restrict__ bhh,
                         float* __restrict__ cb) {
  int d = blockIdx.x, t = threadIdx.x;
  float v = bih[d * G3 + t];
  if (t < 512) v += bhh[d * G3 + t];     // bhh_r, bhh_z additive pre-sigmoid; bhh_n NOT foldable
  cb[d * G3 + t] = v;
}

__global__ __launch_bounds__(256) void k_embed(const int* __restrict__ ids,
    const float* __restrict__ emb, u16* __restrict__ x) {
  int blk = blockIdx.x;            // l*32 + b
  int l = blk >> 5, b = blk & 31;
  int row = ids[b * L_SEQ + l];
  x[(size_t)blk * EMB + threadIdx.x] = f2bf(emb[(size_t)row * EMB + threadIdx.x]);
}

// NT GEMM: C(M,N) = A(M,K)bf16 * B(N,K)bf16 (+bias). TRANS_B: B is (K,N) row-major.
// C_MODE: 0 = fp32, 1 = bf16, 2 = bf16 packed (and scaled by log2e) for k_gru's gi layout.
template<int TRANS_B, int C_MODE, int ADD_BIAS>
__global__ __launch_bounds__(256) void k_gemm(
    const u16* __restrict__ A, const u16* __restrict__ B, void* __restrict__ Cv,
    const float* __restrict__ bias, int K, int lda, int ldb, int ldc,
    long sA, long sB, long sC, long sBias)
{
  __shared__ __align__(16) u16 As[64][40];
  __shared__ __align__(16) u16 Bs[64][40];
  const int z = blockIdx.z;
  A += z * sA; B += z * sB;
  const int m0 = blockIdx.y * 64, n0 = blockIdx.x * 64;
  const int t = threadIdx.x;
  const int wave = t >> 6, lane = t & 63, lhi = lane >> 4, llo = lane & 15;
  f32x4 acc[4] = {};
  const int ar = t >> 2, ak = (t & 3) * 8;
  const int bkr = t >> 3, bnn = (t & 7) * 8;
  for (int k0 = 0; k0 < K; k0 += 32) {
    uint4 av = *(const uint4*)(A + (long)(m0 + ar) * lda + k0 + ak);
    *(uint4*)&As[ar][ak] = av;
    if (!TRANS_B) {
      uint4 bv = *(const uint4*)(B + (long)(n0 + ar) * ldb + k0 + ak);
      *(uint4*)&Bs[ar][ak] = bv;
    } else {
      uint4 bv = *(const uint4*)(B + (long)(k0 + bkr) * ldb + n0 + bnn);
      u16 tmp[8];
      *(uint4*)tmp = bv;
      #pragma unroll
      for (int i = 0; i < 8; i++) Bs[bnn + i][bkr] = tmp[i];
    }
    __syncthreads();
    bf16x8 a = __builtin_bit_cast(bf16x8, *(const uint4*)&As[16 * wave + llo][lhi * 8]);
    #pragma unroll
    for (int j = 0; j < 4; j++) {
      bf16x8 b = __builtin_bit_cast(bf16x8, *(const uint4*)&Bs[16 * j + llo][lhi * 8]);
      acc[j] = __builtin_amdgcn_mfma_f32_16x16x32_bf16(a, b, acc[j], 0, 0, 0);
    }
    __syncthreads();
  }
  #pragma unroll
  for (int j = 0; j < 4; j++) {
    float bv = 0.f;
    if (ADD_BIAS) bv = bias[z * sBias + n0 + 16 * j + llo];
    #pragma unroll
    for (int r = 0; r < 4; r++) {
      long row = m0 + 16 * wave + lhi * 4 + r;
      long col = n0 + 16 * j + llo;
      float vv = acc[j][r] + bv;
      if (C_MODE == 2) {
        // pack for k_gru: dir z, l = row>>5, b = row&31, g = col>>8, cc = col&255
        vv *= LOG2E;
        int b = (int)(row & 31);
        long l = row >> 5;
        int cc = (int)(col & 255), g = (int)(col >> 8);
        long idx = ((l * 2 + (b >> 4)) * 512 + (cc >> 5) * 64 + ((b & 15) >> 2) * 16 + (cc & 15)) * 24
                   + g * 8 + ((cc >> 4) & 1) * 4 + (b & 3);
        ((u16*)Cv)[z * sC + idx] = f2bf(vv);
      } else if (C_MODE == 1) {
        ((u16*)Cv)[z * sC + row * ldc + col] = f2bf(vv);
      } else {
        ((float*)Cv)[z * sC + row * ldc + col] = vv;
      }
    }
  }
}

// GRU recurrence. grid = 4: blockIdx.x = dir*2 + batch_half. 512 threads (8 waves).
// Wave w owns gh cols [32w,32w+32) for all 3 gates. r,z weight tiles (4) in regs;
// n-gate tiles (2) in LDS. Whh/gi/bias pre-scaled by log2e: sigmoid = rcp(1+exp2(-x)).
// Gates computed in MFMA C-layout; h_old in regs; h double-buffered in LDS; 1 barrier/step.
__global__ __launch_bounds__(512, 2) void k_gru(
    const u16* __restrict__ whh, const float* __restrict__ bhh,
    const u16* __restrict__ gi, const float* __restrict__ h0,
    u16* __restrict__ out)
{
  const int dir = blockIdx.x >> 1;
  const int half = blockIdx.x & 1;
  const int b0 = half * 16;
  extern __shared__ __align__(16) char smem[];
  uint4 (*ldsB)[2][8][64] = (uint4(*)[2][8][64])smem;                 // 128 KB
  u16 (*h_lds)[16][264] = (u16(*)[16][264])(smem + 131072);           // 16.5 KB
  const int t = threadIdx.x;
  const int w = t >> 6, lane = t & 63, lhi = lane >> 4, llo = lane & 15;
  const u16* whh_d = whh + dir * G3 * HID;

  // r,z tiles -> registers (tt = g*2+jj, g in {0,1})
  uint4 breg[4][8];
  #pragma unroll
  for (int tt = 0; tt < 4; tt++) {
    const int g = tt >> 1, jj = tt & 1;
    const u16* bp = whh_d + (size_t)(g * 256 + 32 * w + 16 * jj + llo) * HID + lhi * 8;
    #pragma unroll
    for (int kt = 0; kt < 8; kt++) breg[tt][kt] = *(const uint4*)(bp + kt * 32);
  }
  // n tiles -> LDS
  #pragma unroll
  for (int jj = 0; jj < 2; jj++) {
    const u16* bp = whh_d + (size_t)(512 + 32 * w + 16 * jj + llo) * HID + lhi * 8;
    #pragma unroll
    for (int kt = 0; kt < 8; kt++) ldsB[w][jj][kt][lane] = *(const uint4*)(bp + kt * 32);
  }
  // h0 -> h_lds[0] (A layout)
  {
    int m = t >> 5, c0 = (t & 31) * 8;
    const float* hp = h0 + (size_t)(dir * BATCH + b0 + m) * HID + c0;
    float4 f0 = *(const float4*)(hp);
    float4 f1 = *(const float4*)(hp + 4);
    u16 hh[8] = {f2bf(f0.x), f2bf(f0.y), f2bf(f0.z), f2bf(f0.w),
                 f2bf(f1.x), f2bf(f1.y), f2bf(f1.z), f2bf(f1.w)};
    *(uint4*)&h_lds[0][m][c0] = *(uint4*)hh;
  }
  // h_old in C-layout registers
  float hreg[8];
  #pragma unroll
  for (int jj = 0; jj < 2; jj++)
    #pragma unroll
    for (int r = 0; r < 4; r++)
      hreg[jj * 4 + r] = h0[(size_t)(dir * BATCH + b0 + lhi * 4 + r) * HID + 32 * w + 16 * jj + llo];
  const float bn0 = bhh[dir * G3 + 512 + 32 * w + llo] * LOG2E;
  const float bn1 = bhh[dir * G3 + 512 + 32 * w + 16 + llo] * LOG2E;

  const int l0 = dir ? (L_SEQ - 1) : 0;
  const u16* gp = gi + (size_t)dir * 12582912 + (((size_t)l0 * 2 + half) * 512 + t) * 24;
  const long gdelta = dir ? -24576 : 24576;
  u16* ob = out + ((size_t)l0 * BATCH + b0 + lhi * 4) * H2V + dir * HID + 32 * w + llo;
  const long odelta = dir ? -(long)BATCH * H2V : (long)BATCH * H2V;
  __syncthreads();

  for (int s = 0; s < L_SEQ; s++) {
    const int rd = s & 1, wr = rd ^ 1;
    uint4 q0 = *(const uint4*)(gp);
    uint4 q1 = *(const uint4*)(gp + 8);
    uint4 q2 = *(const uint4*)(gp + 16);

    f32x4 acc[6];
    #pragma unroll
    for (int tt = 0; tt < 4; tt++) acc[tt] = (f32x4){0.f, 0.f, 0.f, 0.f};
    acc[4] = (f32x4){bn0, bn0, bn0, bn0};
    acc[5] = (f32x4){bn1, bn1, bn1, bn1};
    #pragma unroll
    for (int kt = 0; kt < 8; kt++) {
      bf16x8 a = __builtin_bit_cast(bf16x8, *(const uint4*)&h_lds[rd][llo][kt * 32 + lhi * 8]);
      uint4 b4 = ldsB[w][0][kt][lane];
      uint4 b5 = ldsB[w][1][kt][lane];
      #pragma unroll
      for (int tt = 0; tt < 4; tt++)
        acc[tt] = __builtin_amdgcn_mfma_f32_16x16x32_bf16(
            a, __builtin_bit_cast(bf16x8, breg[tt][kt]), acc[tt], 0, 0, 0);
      acc[4] = __builtin_amdgcn_mfma_f32_16x16x32_bf16(
          a, __builtin_bit_cast(bf16x8, b4), acc[4], 0, 0, 0);
      acc[5] = __builtin_amdgcn_mfma_f32_16x16x32_bf16(
          a, __builtin_bit_cast(bf16x8, b5), acc[5], 0, 0, 0);
    }

    u16 __attribute__((aligned(16))) arr[24];
    *(uint4*)&arr[0] = q0;
    *(uint4*)&arr[8] = q1;
    *(uint4*)&arr[16] = q2;
    #pragma unroll
    for (int jj = 0; jj < 2; jj++) {
      #pragma unroll
      for (int r = 0; r < 4; r++) {
        const int o = jj * 4 + r;
        float ir = bf2f(arr[o]) + acc[jj][r];              // pre-scaled by log2e
        float iz = bf2f(arr[8 + o]) + acc[2 + jj][r];
        float rr = __builtin_amdgcn_rcpf(1.f + __builtin_amdgcn_exp2f(-ir));
        float zz = __builtin_amdgcn_rcpf(1.f + __builtin_amdgcn_exp2f(-iz));
        float p = bf2f(arr[16 + o]) + rr * acc[4 + jj][r];
        float nn = 2.f * __builtin_amdgcn_rcpf(1.f + __builtin_amdgcn_exp2f(-2.f * p)) - 1.f;
        float hv = nn + zz * (hreg[o] - nn);
        hreg[o] = hv;
        u16 hb = f2bf(hv);
        h_lds[wr][lhi * 4 + r][32 * w + 16 * jj + llo] = hb;
        ob[r * H2V + jj * 16] = hb;
      }
    }
    gp += gdelta;
    ob += odelta;
    __syncthreads();
  }
}

__global__ __launch_bounds__(256) void k_softmax(float* __restrict__ e) {
  const int row = blockIdx.x * 4 + (threadIdx.x >> 6);
  const int lane = threadIdx.x & 63;
  float* p = e + (long)row * NFEAT;
  float v[8];
  #pragma unroll
  for (int i = 0; i < 8; i++) v[i] = p[lane + 64 * i];
  float mx = v[0];
  #pragma unroll
  for (int i = 1; i < 8; i++) mx = fmaxf(mx, v[i]);
  #pragma unroll
  for (int o = 1; o < 64; o <<= 1) mx = fmaxf(mx, __shfl_xor(mx, o, 64));
  float sum = 0.f;
  #pragma unroll
  for (int i = 0; i < 8; i++) { v[i] = __expf(v[i] - mx); sum += v[i]; }
  #pragma unroll
  for (int o = 1; o < 64; o <<= 1) sum += __shfl_xor(sum, o, 64);
  float inv = 1.0f / sum;
  #pragma unroll
  for (int i = 0; i < 8; i++) p[lane + 64 * i] = v[i] * inv;
}

// energy(L,B,F) probs -> attn_out (B,F,L) fp32 and Pb (B,F,L) bf16
__global__ __launch_bounds__(256) void k_transpose(const float* __restrict__ P,
    float* __restrict__ aout, u16* __restrict__ Pb)
{
  const int l0 = blockIdx.x * 64, f0 = blockIdx.y * 64, b = blockIdx.z;
  __shared__ float tile[64][65];
  const int t = threadIdx.x;
  const int ci = t & 63, q = t >> 6;
  #pragma unroll
  for (int s2 = 0; s2 < 16; s2++) {
    int li = q * 16 + s2;
    tile[li][ci] = P[((long)(l0 + li) * BATCH + b) * NFEAT + f0 + ci];
  }
  __syncthreads();
  #pragma unroll
  for (int s2 = 0; s2 < 16; s2++) {
    int f = q * 16 + s2;
    float val = tile[ci][f];
    long idx = ((long)b * NFEAT + f0 + f) * L_SEQ + l0 + ci;
    aout[idx] = val;
    Pb[idx] = f2bf(val);
  }
}

extern "C" void kernel_launch(void* const* d_in, const int* in_sizes, int n_in,
                              void* d_out, int out_size, void* d_ws, size_t ws_size,
                              hipStream_t stream)
{
  const int* ids      = (const int*)d_in[0];
  const float* hidden = (const float*)d_in[2];
  const float* fe     = (const float*)d_in[3];
  const float* emb    = (const float*)d_in[4];
  const float* wih0   = (const float*)d_in[5];
  const float* whh0   = (const float*)d_in[6];
  const float* bih0   = (const float*)d_in[7];
  const float* bhh0   = (const float*)d_in[8];
  const float* wih1   = (const float*)d_in[9];
  const float* whh1   = (const float*)d_in[10];
  const float* bih1   = (const float*)d_in[11];
  const float* bhh1   = (const float*)d_in[12];
  const float* law    = (const float*)d_in[13];
  const float* lab    = (const float*)d_in[14];
  const float* faw    = (const float*)d_in[15];
  const float* fab    = (const float*)d_in[16];
  const float* vmat   = (const float*)d_in[17];

  char* w = (char*)d_ws;
  size_t o = 0;
  auto alloc = [&](size_t elems, size_t esz) {
    void* p = w + o; o = (o + elems * esz + 255) & ~(size_t)255; return p;
  };
  u16* wih0b = (u16*)alloc((size_t)2 * 768 * 256, 2);
  u16* whh0b = (u16*)alloc((size_t)2 * 768 * 256, 2);
  u16* wih1b = (u16*)alloc((size_t)2 * 768 * 512, 2);
  u16* whh1b = (u16*)alloc((size_t)2 * 768 * 256, 2);
  u16* lawb  = (u16*)alloc((size_t)256 * 512, 2);
  u16* fawb  = (u16*)alloc((size_t)256 * 512, 2);
  u16* vb    = (u16*)alloc((size_t)128 * 256, 2);
  u16* feb   = (u16*)alloc((size_t)384 * 256, 2);
  u16* xb    = (u16*)alloc((size_t)16384 * 256, 2);
  u16* gi0   = (u16*)alloc((size_t)2 * 16384 * 768, 2);
  u16* out0  = (u16*)alloc((size_t)16384 * 512, 2);
  u16* gi1   = (u16*)alloc((size_t)2 * 16384 * 768, 2);
  u16* rnn   = (u16*)alloc((size_t)16384 * 512, 2);
  u16* wh    = (u16*)alloc((size_t)16384 * 256, 2);
  u16* wh2   = (u16*)alloc((size_t)16384 * 256, 2);
  float* energy = (float*)alloc((size_t)16384 * 512, 4);
  u16* Pb    = (u16*)alloc((size_t)16384 * 512, 2);
  float* cbias0 = (float*)alloc((size_t)2 * 768, 4);
  float* cbias1 = (float*)alloc((size_t)2 * 768, 4);

  k_cvt<<<96, 256, 0, stream>>>(wih0, wih0b, 2 * 768 * 256, 1.0f);
  k_cvt<<<96, 256, 0, stream>>>(whh0, whh0b, 2 * 768 * 256, LOG2E);
  k_cvt<<<192, 256, 0, stream>>>(wih1, wih1b, 2 * 768 * 512, 1.0f);
  k_cvt<<<96, 256, 0, stream>>>(whh1, whh1b, 2 * 768 * 256, LOG2E);
  k_cvt<<<32, 256, 0, stream>>>(law, lawb, 256 * 512, 1.0f);
  k_cvt<<<32, 256, 0, stream>>>(faw, fawb, 256 * 512, 1.0f);
  k_cvt<<<8, 256, 0, stream>>>(vmat, vb, 128 * 256, 1.0f);
  k_cvt<<<24, 256, 0, stream>>>(fe, feb, 384 * 256, 1.0f);
  k_mkbias<<<2, 768, 0, stream>>>(bih0, bhh0, cbias0);
  k_mkbias<<<2, 768, 0, stream>>>(bih1, bhh1, cbias1);
  k_embed<<<16384, 256, 0, stream>>>(ids, emb, xb);

  // gi0 = (x @ wih0^T + (bih0 + bhh0[r,z])) * log2e, packed for k_gru
  k_gemm<0, 2, 1><<<dim3(12, 256, 2), 256, 0, stream>>>(xb, wih0b, gi0, cbias0,
      256, 256, 256, 768, 0L, 768L * 256, 12582912L, 768L);
  k_gru<<<4, 512, 147968, stream>>>(whh0b, bhh0, gi0, hidden, out0);

  // gi1 = (out0 @ wih1^T + (bih1 + bhh1[r,z])) * log2e, packed
  k_gemm<0, 2, 1><<<dim3(12, 256, 2), 256, 0, stream>>>(out0, wih1b, gi1, cbias1,
      512, 512, 512, 768, 0L, 768L * 512, 12582912L, 768L);
  k_gru<<<4, 512, 147968, stream>>>(whh1b, bhh1, gi1, hidden + 2 * 32 * 256, rnn);

  // wh = rnn @ la_w^T + la_b (bf16), wh2 = rnn @ fa_w^T + fa_b (bf16)
  k_gemm<0, 1, 1><<<dim3(4, 256, 1), 256, 0, stream>>>(rnn, lawb, wh, lab,
      512, 512, 512, 256, 0L, 0L, 0L, 0L);
  k_gemm<0, 1, 1><<<dim3(4, 256, 1), 256, 0, stream>>>(rnn, fawb, wh2, fab,
      512, 512, 512, 256, 0L, 0L, 0L, 0L);
  // vwh -> energy[:,384:512] ; fwh -> energy[:,0:384]  (fp32)
  k_gemm<0, 0, 0><<<dim3(2, 256, 1), 256, 0, stream>>>(wh, vb, energy + 384, nullptr,
      256, 256, 256, 512, 0L, 0L, 0L, 0L);
  k_gemm<0, 0, 0><<<dim3(6, 256, 1), 256, 0, stream>>>(wh2, feb, energy, nullptr,
      256, 256, 256, 512, 0L, 0L, 0L, 0L);

  k_softmax<<<4096, 256, 0, stream>>>(energy);

  float* attn_out = (float*)d_out + (size_t)32 * 512 * 512;
  k_transpose<<<dim3(8, 8, 32), 256, 0, stream>>>(energy, attn_out, Pb);

  // context[b] = P[b](F,L) @ rnn(:,b,:)(L,2H)  -> d_out (B,F,2H) fp32
  k_gemm<1, 0, 0><<<dim3(8, 8, 32), 256, 0, stream>>>(Pb, rnn, (float*)d_out, nullptr,
      512, 512, 16384, 512, (long)512 * 512, 512L, (long)512 * 512, 0L);
}